// Round 2
// baseline (910.080 us; speedup 1.0000x reference)
//
#include <hip/hip_runtime.h>
#include <stdint.h>

// ParallelFcWithAttention: B=16384, F=10, D=512, H=8, DH=64
// R2: kern_attn rewritten wave-private — each wave owns heads {w, w+4} end-to-end:
//   stages its own B slabs (dbuf, explicit vmcnt waits, NO __syncthreads in K-loop),
//   MFMA scores (Q@K^T) and PV (attn@vT) instead of scalar attention.
// MFMA frag convention (m89-verified): A/B frag = [row][k contig 8], C/D: row=(lane>>4)*4+r, col=lane&15.

typedef __bf16 bf16;
typedef __bf16 bf16x8 __attribute__((ext_vector_type(8)));
typedef float f32x4 __attribute__((ext_vector_type(4)));

#define EPS 1e-5f

static constexpr size_t O_ELEMS   = (size_t)16384 * 10 * 512;   // 83,886,080
static constexpr size_t O_BYTES   = O_ELEMS * 2;                // 167,772,160
static constexpr size_t WQKV_BYTES = (size_t)8 * 192 * 512 * 2;

__device__ __forceinline__ void async_copy16(void* lds, const void* g) {
  __builtin_amdgcn_global_load_lds(
      (const __attribute__((address_space(1))) uint32_t*)g,
      (__attribute__((address_space(3))) uint32_t*)lds, 16, 0, 0);
}
// gfx9 waitcnt encoding: vmcnt[3:0]|[15:14], expcnt[6:4], lgkmcnt[11:8]. 0x0F70 = only-vmcnt.
__device__ __forceinline__ void wait_vmcnt_0()  { __builtin_amdgcn_s_waitcnt(0x0F70); }
__device__ __forceinline__ void wait_vmcnt_12() { __builtin_amdgcn_s_waitcnt(0x0F70 | 12); }

// ---------------- pack weights to bf16 ----------------
__global__ __launch_bounds__(256) void pack_weights(
    const float* __restrict__ Wq, const float* __restrict__ Wk,
    const float* __restrict__ Wv, const float* __restrict__ Wo,
    bf16* __restrict__ wqkv, bf16* __restrict__ wob) {
  int idx = blockIdx.x * 256 + threadIdx.x;
#pragma unroll
  for (int u = 0; u < 4; ++u) {
    int i = idx + u * 262144;
    if (i < 786432) {
      int pr = i >> 9, k = i & 511;
      int h = pr / 192, w = pr - h * 192;
      int t = w >> 6, r = w & 63;
      const float* src = (t == 0) ? Wq : ((t == 1) ? Wk : Wv);
      wqkv[i] = (bf16)src[(h * 64 + r) * 512 + k];
    } else {
      int j = i - 786432;
      wob[j] = (bf16)Wo[j];
    }
  }
}

// ---------------- fused P + QKV + attention, wave-private heads ----------------
// LDS: sA = P tile [8 s64][48 rows][8 chunk16] XOR-swizzled (shared, read-only after 1 barrier)
//      sW[w] = 24576 B wave-private:
//        GEMM phase: B-slab dbuf 2 x [192 rows][32k] (2 x 12288), global-side chunk swizzle
//        attn phase: qbuf[48][72]bf16 @0 (overlaid by attn matrix) | kbuf[48][72] @6912 | vT[64][72] @13824
__global__ __launch_bounds__(256, 1) void kern_attn(
    const float* __restrict__ x, const float* __restrict__ Wf,
    const float* __restrict__ bfv, const bf16* __restrict__ wqkv,
    const float* __restrict__ bq, const float* __restrict__ bk,
    const float* __restrict__ bv, bf16* __restrict__ O) {
  __shared__ __align__(16) char sA[49152];
  __shared__ __align__(16) char sW[4][24576];

  const int tid = threadIdx.x;
  const int wave = tid >> 6;
  const int lane = tid & 63;
  const int lm = lane & 15;
  const int lg = lane >> 4;
  const int b0 = blockIdx.x * 4;

  // ---- P = relu(x*Wf + bf) into sA (rows >=40 zeroed), chunk' = chunk ^ (row&7) ----
#pragma unroll
  for (int it = 0; it < 12; ++it) {
    int c = tid + it * 256;
    int s = c / 384, rem = c - s * 384;
    int r = rem >> 3, kcp = rem & 7;
    int kc = kcp ^ (r & 7);
    int k = s * 64 + kc * 8;
    bf16x8 pv;
    if (r < 40) {
      int bl = r / 10, f = r - bl * 10;
      float xv = x[(b0 + bl) * 10 + f];
      const float* wf = Wf + f * 512 + k;
      const float* bp = bfv + f * 512 + k;
#pragma unroll
      for (int j = 0; j < 8; ++j) pv[j] = (bf16)fmaxf(xv * wf[j] + bp[j], 0.f);
    } else {
#pragma unroll
      for (int j = 0; j < 8; ++j) pv[j] = (bf16)0.f;
    }
    *(bf16x8*)(sA + s * 6144 + r * 128 + kcp * 16) = pv;
  }
  __syncthreads();   // the ONLY workgroup barrier

  char* reg  = sW[wave];
  char* qbuf = reg;            // also attn matrix later
  char* kbuf = reg + 6912;
  char* vtb  = reg + 13824;

  const int rlo = lane >> 2, cpn = lane & 3;
  const int bswiz = ((lg ^ (lm & 3) ^ ((lm >> 2) & 3)) << 4);

  for (int hh = 0; hh < 2; ++hh) {
    const int h = wave + hh * 4;
    const bf16* wh = wqkv + (size_t)h * 192 * 512;

    // preload biases (col = nt*16+lm)
    float bias[12];
#pragma unroll
    for (int nt = 0; nt < 12; ++nt) {
      int col = nt * 16 + lm;
      const float* bp = (col < 64) ? (bq + h * 64 + col)
                       : (col < 128) ? (bk + h * 64 + col - 64)
                                     : (bv + h * 64 + col - 128);
      bias[nt] = *bp;
    }

    f32x4 acc[3][12];
#pragma unroll
    for (int i = 0; i < 3; ++i)
#pragma unroll
      for (int j = 0; j < 12; ++j) { f32x4 z = {0.f, 0.f, 0.f, 0.f}; acc[i][j] = z; }

    // stage slab 0
#pragma unroll
    for (int j = 0; j < 12; ++j) {
      int r = j * 16 + rlo;
      int cg = cpn ^ (r & 3) ^ ((r >> 2) & 3);
      async_copy16(reg + j * 1024, wh + (size_t)r * 512 + cg * 8);
    }

    for (int s = 0; s < 16; ++s) {
      if (s < 15) {
        char* dst = reg + ((s + 1) & 1) * 12288;
        int ks = (s + 1) * 32;
#pragma unroll
        for (int j = 0; j < 12; ++j) {
          int r = j * 16 + rlo;
          int cg = cpn ^ (r & 3) ^ ((r >> 2) & 3);
          async_copy16(dst + j * 1024, wh + (size_t)r * 512 + ks + cg * 8);
        }
        wait_vmcnt_12();       // oldest 12 (slab s) complete; slab s+1 in flight
      } else {
        wait_vmcnt_0();
      }
      const char* buf = reg + (s & 1) * 12288;
      const char* sAs = sA + (s >> 1) * 6144;
      int kc = ((s & 1) << 2) | lg;
      bf16x8 af[3];
#pragma unroll
      for (int mt = 0; mt < 3; ++mt) {
        int m = mt * 16 + lm;
        af[mt] = *(const bf16x8*)(sAs + m * 128 + ((kc ^ (m & 7)) << 4));
      }
#pragma unroll
      for (int nt = 0; nt < 12; ++nt) {
        bf16x8 bfr = *(const bf16x8*)(buf + (nt * 16 + lm) * 64 + bswiz);
#pragma unroll
        for (int mt = 0; mt < 3; ++mt)
          acc[mt][nt] = __builtin_amdgcn_mfma_f32_16x16x32_bf16(af[mt], bfr, acc[mt][nt], 0, 0, 0);
      }
    }

    // ---- spill q(/8), k, vT to wave-private LDS (staging bufs dead) ----
    {  // zero vT pad cols j in [40,64) (NaN guard for PV)
      f32x4 z4 = {0.f, 0.f, 0.f, 0.f};
      *(f32x4*)(vtb + lane * 144 + 80)  = z4;
      *(f32x4*)(vtb + lane * 144 + 96)  = z4;
      *(f32x4*)(vtb + lane * 144 + 112) = z4;
    }
#pragma unroll
    for (int nt = 0; nt < 12; ++nt) {
      int col = nt * 16 + lm;
#pragma unroll
      for (int mt = 0; mt < 3; ++mt)
#pragma unroll
        for (int r = 0; r < 4; ++r) {
          int row = mt * 16 + lg * 4 + r;
          if (row < 40) {
            float v = acc[mt][nt][r] + bias[nt];
            if (col < 64)       *(bf16*)(qbuf + row * 144 + col * 2) = (bf16)(v * 0.125f);
            else if (col < 128) *(bf16*)(kbuf + row * 144 + (col - 64) * 2) = (bf16)v;
            else                *(bf16*)(vtb + (col - 128) * 144 + row * 2) = (bf16)v;
          }
        }
    }

    // ---- scores S = (q/8) @ k^T  (M=48,N=48,K=64) ----
    f32x4 accS[3][3];
#pragma unroll
    for (int i = 0; i < 3; ++i)
#pragma unroll
      for (int j = 0; j < 3; ++j) { f32x4 z = {0.f, 0.f, 0.f, 0.f}; accS[i][j] = z; }
#pragma unroll
    for (int kk = 0; kk < 2; ++kk) {
      bf16x8 aq[3], bk8[3];
#pragma unroll
      for (int mt = 0; mt < 3; ++mt)
        aq[mt] = *(const bf16x8*)(qbuf + (mt * 16 + lm) * 144 + kk * 64 + lg * 16);
#pragma unroll
      for (int nt = 0; nt < 3; ++nt)
        bk8[nt] = *(const bf16x8*)(kbuf + (nt * 16 + lm) * 144 + kk * 64 + lg * 16);
#pragma unroll
      for (int mt = 0; mt < 3; ++mt)
#pragma unroll
        for (int nt = 0; nt < 3; ++nt)
          accS[mt][nt] = __builtin_amdgcn_mfma_f32_16x16x32_bf16(aq[mt], bk8[nt], accS[mt][nt], 0, 0, 0);
    }

    // ---- in-register masked softmax (block-diag over batches), write e -> attn (overlays qbuf) ----
    float inv_r[3][4];
#pragma unroll
    for (int mt = 0; mt < 3; ++mt)
#pragma unroll
      for (int r = 0; r < 4; ++r) {
        int row = mt * 16 + lg * 4 + r;
        int c0 = (row / 10) * 10;
        float vv[3]; bool val[3];
#pragma unroll
        for (int nt = 0; nt < 3; ++nt) {
          int col = nt * 16 + lm;
          vv[nt] = accS[mt][nt][r];
          val[nt] = ((unsigned)(col - c0)) < 10u;
        }
        float m = -3.0e38f;
#pragma unroll
        for (int nt = 0; nt < 3; ++nt) m = val[nt] ? fmaxf(m, vv[nt]) : m;
#pragma unroll
        for (int off = 1; off < 16; off <<= 1) m = fmaxf(m, __shfl_xor(m, off));
        float e[3], ssum = 0.f;
#pragma unroll
        for (int nt = 0; nt < 3; ++nt) { e[nt] = val[nt] ? __expf(vv[nt] - m) : 0.f; ssum += e[nt]; }
#pragma unroll
        for (int off = 1; off < 16; off <<= 1) ssum += __shfl_xor(ssum, off);
        inv_r[mt][r] = 1.0f / ssum;
#pragma unroll
        for (int nt = 0; nt < 3; ++nt)
          *(bf16*)(qbuf + row * 144 + (nt * 16 + lm) * 2) = (bf16)e[nt];
        *(bf16*)(qbuf + row * 144 + (48 + lm) * 2) = (bf16)0.f;   // zero cols 48..63
      }

    // ---- PV: O = attn @ vT^T  (M=48,N=64,K=64) ----
    f32x4 accO[3][4];
#pragma unroll
    for (int i = 0; i < 3; ++i)
#pragma unroll
      for (int j = 0; j < 4; ++j) { f32x4 z = {0.f, 0.f, 0.f, 0.f}; accO[i][j] = z; }
#pragma unroll
    for (int kk = 0; kk < 2; ++kk) {
      bf16x8 aa[3], bv8[4];
#pragma unroll
      for (int mt = 0; mt < 3; ++mt)
        aa[mt] = *(const bf16x8*)(qbuf + (mt * 16 + lm) * 144 + kk * 64 + lg * 16);
#pragma unroll
      for (int nt = 0; nt < 4; ++nt)
        bv8[nt] = *(const bf16x8*)(vtb + (nt * 16 + lm) * 144 + kk * 64 + lg * 16);
#pragma unroll
      for (int mt = 0; mt < 3; ++mt)
#pragma unroll
        for (int nt = 0; nt < 4; ++nt)
          accO[mt][nt] = __builtin_amdgcn_mfma_f32_16x16x32_bf16(aa[mt], bv8[nt], accO[mt][nt], 0, 0, 0);
    }
    // epilogue: scale by row inverse-sum, store bf16
#pragma unroll
    for (int mt = 0; mt < 3; ++mt)
#pragma unroll
      for (int r = 0; r < 4; ++r) {
        int row = mt * 16 + lg * 4 + r;
        if (row < 40) {
          float scl = inv_r[mt][r];
#pragma unroll
          for (int nt = 0; nt < 4; ++nt) {
            int d = nt * 16 + lm;
            O[(size_t)(b0 * 10 + row) * 512 + h * 64 + d] = (bf16)(accO[mt][nt][r] * scl);
          }
        }
      }
  }
}

// ---------------- O @ Wo.T + bo -> LayerNorm -> sum over F (unchanged) ----------------
__global__ __launch_bounds__(256, 2) void kern_out(
    const bf16* __restrict__ O, const bf16* __restrict__ wob,
    const float* __restrict__ bo, const float* __restrict__ gamma,
    const float* __restrict__ beta, float* __restrict__ out) {
  __shared__ __align__(16) char sAB[71680];
  __shared__ float partial[48][4][2];
  __shared__ float stats[48][2];
  char* As = sAB;
  char* Bs = sAB + 6144;
  bf16* lnb = (bf16*)sAB;

  const int tid = threadIdx.x;
  const int wave = tid >> 6, lane = tid & 63;
  const int lm = lane & 15, lg = lane >> 4;
  const int m0 = blockIdx.x * 40;

  f32x4 acc[3][8];
#pragma unroll
  for (int i = 0; i < 3; ++i)
#pragma unroll
    for (int j = 0; j < 8; ++j) { f32x4 z = {0.f, 0.f, 0.f, 0.f}; acc[i][j] = z; }

  const int lr = lane >> 3;
  const int kcp2 = lane & 7;
  const int kcg = kcp2 ^ lr;

  for (int s = 0; s < 8; ++s) {
    {
      int rr = wave * 8 + lr;
      int rm = min(rr, 39);
      async_copy16(As + wave * 1024, O + (size_t)(m0 + rm) * 512 + s * 64 + kcg * 8);
      if (wave < 2) {
        int rr2 = (4 + wave) * 8 + lr;
        int rm2 = min(rr2, 39);
        async_copy16(As + (4 + wave) * 1024, O + (size_t)(m0 + rm2) * 512 + s * 64 + kcg * 8);
      }
    }
#pragma unroll
    for (int jb = 0; jb < 16; ++jb) {
      int rb = wave + 4 * jb;
      int n = rb * 8 + lr;
      async_copy16(Bs + rb * 1024, wob + (size_t)n * 512 + s * 64 + kcg * 8);
    }
    __syncthreads();
#pragma unroll
    for (int kk = 0; kk < 2; ++kk) {
      int kcl = kk * 4 + lg;
      bf16x8 af[3], bfr[8];
#pragma unroll
      for (int mt = 0; mt < 3; ++mt) {
        int m = mt * 16 + lm;
        af[mt] = *(const bf16x8*)(As + m * 128 + ((kcl ^ (m & 7)) << 4));
      }
#pragma unroll
      for (int nt = 0; nt < 8; ++nt) {
        int n = wave * 128 + nt * 16 + lm;
        bfr[nt] = *(const bf16x8*)(Bs + n * 128 + ((kcl ^ (n & 7)) << 4));
      }
#pragma unroll
      for (int mt = 0; mt < 3; ++mt)
#pragma unroll
        for (int nt = 0; nt < 8; ++nt)
          acc[mt][nt] = __builtin_amdgcn_mfma_f32_16x16x32_bf16(af[mt], bfr[nt], acc[mt][nt], 0, 0, 0);
    }
    __syncthreads();
  }

#pragma unroll
  for (int nt = 0; nt < 8; ++nt) {
    int col = wave * 128 + nt * 16 + lm;
    float bb = bo[col];
#pragma unroll
    for (int mt = 0; mt < 3; ++mt)
#pragma unroll
      for (int r = 0; r < 4; ++r) acc[mt][nt][r] += bb;
  }

#pragma unroll
  for (int mt = 0; mt < 3; ++mt)
#pragma unroll
    for (int r = 0; r < 4; ++r) {
      float s1 = 0.f, s2 = 0.f;
#pragma unroll
      for (int nt = 0; nt < 8; ++nt) { float v = acc[mt][nt][r]; s1 += v; s2 += v * v; }
#pragma unroll
      for (int off = 1; off < 16; off <<= 1) {
        s1 += __shfl_xor(s1, off);
        s2 += __shfl_xor(s2, off);
      }
      if (lm == 0) {
        int row = mt * 16 + lg * 4 + r;
        partial[row][wave][0] = s1;
        partial[row][wave][1] = s2;
      }
    }
  __syncthreads();
  if (tid < 48) {
    float s1 = partial[tid][0][0] + partial[tid][1][0] + partial[tid][2][0] + partial[tid][3][0];
    float s2 = partial[tid][0][1] + partial[tid][1][1] + partial[tid][2][1] + partial[tid][3][1];
    float mu = s1 * (1.f / 512.f);
    float var = s2 * (1.f / 512.f) - mu * mu;
    stats[tid][0] = mu;
    stats[tid][1] = rsqrtf(var + EPS);
  }
  __syncthreads();
#pragma unroll
  for (int mt = 0; mt < 3; ++mt)
#pragma unroll
    for (int r = 0; r < 4; ++r) {
      int row = mt * 16 + lg * 4 + r;
      float mu = stats[row][0], rr = stats[row][1];
#pragma unroll
      for (int nt = 0; nt < 8; ++nt) {
        int col = wave * 128 + nt * 16 + lm;
        lnb[row * 520 + col] = (bf16)((acc[mt][nt][r] - mu) * rr);
      }
    }
  __syncthreads();
#pragma unroll
  for (int u = 0; u < 8; ++u) {
    int id = tid + u * 256;
    int b = id >> 9, n = id & 511;
    float ssum = 0.f;
#pragma unroll
    for (int f = 0; f < 10; ++f) ssum += (float)lnb[(b * 10 + f) * 520 + n];
    out[(size_t)(blockIdx.x * 4 + b) * 512 + n] = gamma[n] * ssum + 10.f * beta[n];
  }
}

extern "C" void kernel_launch(void* const* d_in, const int* in_sizes, int n_in,
                              void* d_out, int out_size, void* d_ws, size_t ws_size,
                              hipStream_t stream) {
  const float* x     = (const float*)d_in[0];
  const float* Wf    = (const float*)d_in[1];
  const float* bfv   = (const float*)d_in[2];
  const float* Wq    = (const float*)d_in[3];
  const float* Wk    = (const float*)d_in[4];
  const float* Wv    = (const float*)d_in[5];
  const float* bq    = (const float*)d_in[6];
  const float* bk    = (const float*)d_in[7];
  const float* bv    = (const float*)d_in[8];
  const float* Wo    = (const float*)d_in[9];
  const float* bo    = (const float*)d_in[10];
  const float* gamma = (const float*)d_in[11];
  const float* beta  = (const float*)d_in[12];
  float* out = (float*)d_out;

  char* ws = (char*)d_ws;
  bf16* O    = (bf16*)ws;
  bf16* wqkv = (bf16*)(ws + O_BYTES);
  bf16* wob  = (bf16*)(ws + O_BYTES + WQKV_BYTES);

  pack_weights<<<1024, 256, 0, stream>>>(Wq, Wk, Wv, Wo, wqkv, wob);
  kern_attn<<<4096, 256, 0, stream>>>(x, Wf, bfv, wqkv, bq, bk, bv, O);
  kern_out<<<4096, 256, 0, stream>>>(O, wob, bo, gamma, beta, out);
}